// Round 1
// baseline (1556.409 us; speedup 1.0000x reference)
//
#include <hip/hip_runtime.h>
#include <hip/hip_fp16.h>

#define H 1024
#define NLEV 17
#define OD 5
#define TOTD 85
#define PW 128
#define NB 4096

typedef _Float16 half8 __attribute__((ext_vector_type(8)));
typedef float f32x4 __attribute__((ext_vector_type(4)));

__device__ __forceinline__ void g2l16(const void* g, void* l) {
  __builtin_amdgcn_global_load_lds((const __attribute__((address_space(1))) unsigned*)g,
                                   (__attribute__((address_space(3))) unsigned*)l, 16, 0, 0);
}

// C(8192x1024) = act(A(8192, K) @ W + bias), W given as W^T [n][k] f16.
// Rows < 4096 use B0/bias0 (forward dir), rows >= 4096 use B1/bias1.
template<int KSTEPS, bool RELU>
__global__ __launch_bounds__(256, 2)
void gemm_k(const _Float16* __restrict__ A, int ldaB,
            const _Float16* __restrict__ B0, const _Float16* __restrict__ B1, int ldbB,
            const float* __restrict__ bias0, const float* __restrict__ bias1,
            _Float16* __restrict__ C) {
  __shared__ _Float16 sA[128 * 64];
  __shared__ _Float16 sB[128 * 64];
  const int tid = threadIdx.x;
  const int lane = tid & 63;
  const int wave = tid >> 6;
  const int wm = wave >> 1, wn = wave & 1;
  const int mt = blockIdx.x, nt = blockIdx.y;
  const _Float16* Bp = (mt < 32) ? B0 : B1;
  const float* bias = (mt < 32) ? bias0 : bias1;

  char* sAc = (char*)sA;
  char* sBc = (char*)sB;

  const int srow = (lane >> 3);       // row-in-chunk 0..7
  const int scb = (lane & 7) << 4;    // byte chunk 0..112

  f32x4 acc[4][4];
#pragma unroll
  for (int m = 0; m < 4; ++m)
#pragma unroll
    for (int n = 0; n < 4; ++n) acc[m][n] = 0.f;

  const char* Ab = (const char*)A + (size_t)(mt * 128) * ldaB;
  const char* Bb = (const char*)Bp + (size_t)(nt * 128) * ldbB;

  for (int ks = 0; ks < KSTEPS; ++ks) {
    const int kB = ks << 7;  // byte offset of this K-step
#pragma unroll
    for (int t = 0; t < 4; ++t) {
      int chunk = wave * 4 + t;       // 0..15, wave-uniform
      int row = chunk * 8 + srow;     // 0..127
      int off = kB + (scb ^ ((row & 7) << 4));  // pre-swizzled source
      g2l16(Ab + (size_t)row * ldaB + off, sAc + chunk * 1024);
      g2l16(Bb + (size_t)row * ldbB + off, sBc + chunk * 1024);
    }
    __syncthreads();
#pragma unroll
    for (int h = 0; h < 2; ++h) {
      half8 af[4], bf[4];
      int kb = h * 64 + ((lane >> 4) << 4);
#pragma unroll
      for (int m = 0; m < 4; ++m) {
        int row = wm * 64 + m * 16 + (lane & 15);
        af[m] = *(const half8*)(sAc + row * 128 + (kb ^ ((row & 7) << 4)));
      }
#pragma unroll
      for (int n = 0; n < 4; ++n) {
        int row = wn * 64 + n * 16 + (lane & 15);
        bf[n] = *(const half8*)(sBc + row * 128 + (kb ^ ((row & 7) << 4)));
      }
#pragma unroll
      for (int m = 0; m < 4; ++m)
#pragma unroll
        for (int n = 0; n < 4; ++n)
          acc[m][n] = __builtin_amdgcn_mfma_f32_16x16x32_f16(af[m], bf[n], acc[m][n], 0, 0, 0);
    }
    __syncthreads();
  }
  // epilogue: C/D layout col=lane&15, row=(lane>>4)*4+reg
  const int r0 = mt * 128 + wm * 64 + (lane >> 4) * 4;
#pragma unroll
  for (int n = 0; n < 4; ++n) {
    int col = nt * 128 + wn * 64 + n * 16 + (lane & 15);
    float bv = bias[col];
#pragma unroll
    for (int m = 0; m < 4; ++m) {
      int rbase = r0 + m * 16;
#pragma unroll
      for (int r = 0; r < 4; ++r) {
        float v = acc[m][n][r] + bv;
        if (RELU) v = v > 0.f ? v : 0.f;
        C[(size_t)(rbase + r) * H + col] = (_Float16)v;
      }
    }
  }
}

// out_i = h @ Wout[lev] + bout[lev]; write to tot (fp32) and append to P (f16)
__global__ __launch_bounds__(256)
void outproj_k(const _Float16* __restrict__ h3,
               const float* __restrict__ Wout_f, const float* __restrict__ Wout_b,
               const float* __restrict__ bout_f, const float* __restrict__ bout_b,
               int lev, float* __restrict__ tot, _Float16* __restrict__ P) {
  int gw = blockIdx.x * 4 + (threadIdx.x >> 6);  // 0..8191
  int lane = threadIdx.x & 63;
  int dir = gw >> 12;
  int b = gw & 4095;
  const _Float16* hr = h3 + (size_t)gw * H;
  const float* Wo = (dir ? Wout_b : Wout_f) + (size_t)lev * H * OD;
  const float* bo = (dir ? bout_b : bout_f) + lev * OD;
  float acc[OD] = {0.f, 0.f, 0.f, 0.f, 0.f};
  for (int j = 0; j < 16; ++j) {
    int k = j * 64 + lane;
    float hv = (float)hr[k];
#pragma unroll
    for (int d = 0; d < OD; ++d) acc[d] += hv * Wo[k * OD + d];
  }
#pragma unroll
  for (int off = 32; off; off >>= 1)
#pragma unroll
    for (int d = 0; d < OD; ++d) acc[d] += __shfl_xor(acc[d], off);
  if (lane == 0) {
#pragma unroll
    for (int d = 0; d < OD; ++d) {
      float v = acc[d] + bo[d];
      tot[(size_t)dir * NB * TOTD + (size_t)b * TOTD + lev * OD + d] = v;
      P[((size_t)(dir * NB + b)) * PW + 16 + OD * lev + d] = (_Float16)v;
    }
  }
}

__global__ __launch_bounds__(128)
void attn_k(const float* __restrict__ tot, const float* __restrict__ W1,
            const float* __restrict__ W2, const float* __restrict__ W3,
            const float* __restrict__ W4, const float* __restrict__ b4,
            float* __restrict__ out) {
  __shared__ float tf[5][17], tbr[5][17];
  __shared__ float q[17][5], k2[5][17], vv[17][5];
  __shared__ float sc[17][17];
  __shared__ float res[85];
  int b = blockIdx.x, tid = threadIdx.x;
  const float* tfp = tot + (size_t)b * TOTD;
  const float* tbp = tot + (size_t)NB * TOTD + (size_t)b * TOTD;
  if (tid < 85) {
    int c = tid / 17, t = tid % 17;
    tf[c][t] = tfp[tid];
    tbr[c][t] = tbp[c * 17 + (16 - t)];  // reversed t
  }
  __syncthreads();
  if (tid < 85) {
    int t = tid / 5, e = tid % 5;
    float qa = 0, ka = 0, va = 0;
#pragma unroll
    for (int c = 0; c < 5; ++c) {
      qa += tf[c][t] * W1[c * 5 + e];
      ka += tbr[c][t] * W2[c * 5 + e];
      va += tbr[c][t] * W3[c * 5 + e];
    }
    q[t][e] = qa; k2[e][t] = ka; vv[t][e] = va;
  }
  __syncthreads();
  for (int idx = tid; idx < 289; idx += 128) {
    int t = idx / 17, s = idx % 17;
    float a = 0;
#pragma unroll
    for (int e = 0; e < 5; ++e) a += q[t][e] * k2[e][s];
    sc[t][s] = a;
  }
  __syncthreads();
  if (tid < 17) {  // softmax over axis t (axis=1), per column s
    int s = tid;
    float m = -1e30f;
#pragma unroll
    for (int t = 0; t < 17; ++t) m = fmaxf(m, sc[t][s]);
    float ex[17];
    float sum = 0;
#pragma unroll
    for (int t = 0; t < 17; ++t) { ex[t] = expf(sc[t][s] - m); sum += ex[t]; }
    float inv = 1.f / sum;
#pragma unroll
    for (int t = 0; t < 17; ++t) sc[t][s] = ex[t] * inv;
  }
  __syncthreads();
  if (tid < 85) {
    int t = tid / 5, e = tid % 5;
    float a = 0;
#pragma unroll
    for (int s = 0; s < 17; ++s) a += sc[t][s] * vv[s][e];
    res[tid] = a;
  }
  __syncthreads();
  if (tid < 85) {
    float a = b4[tid];
    for (int s = 0; s < 85; ++s) a += res[s] * W4[s * 85 + tid];
    out[(size_t)b * TOTD + tid] = a;
  }
}

__global__ __launch_bounds__(256)
void prep_wblk(const float* __restrict__ Wblk, _Float16* __restrict__ WblkT) {
  int idx = blockIdx.x * 256 + threadIdx.x;  // < 3*1024*1024
  int j = idx >> 20;
  int rem = idx & 1048575;
  int n = rem >> 10, k = rem & 1023;
  WblkT[idx] = (_Float16)Wblk[((size_t)j << 20) + ((size_t)k << 10) + n];
}

__global__ __launch_bounds__(256)
void prep_win(const float* __restrict__ Wf, const float* __restrict__ Wb,
              _Float16* __restrict__ WT) {
  int idx = blockIdx.x * 256 + threadIdx.x;  // < 2*17*1024*128
  int d = idx / (17 * 1024 * 128);
  int rem = idx % (17 * 1024 * 128);
  int i = rem / (1024 * 128);
  int r2 = rem % (1024 * 128);
  int n = r2 >> 7, k = r2 & 127;
  const float* W = d ? Wb : Wf;
  WT[idx] = (k < 96) ? (_Float16)W[((size_t)i * 96 + k) * 1024 + n] : (_Float16)0.f;
}

__global__ __launch_bounds__(256)
void prep_p(const float* __restrict__ x, _Float16* __restrict__ P) {
  int idx = blockIdx.x * 256 + threadIdx.x;  // < 8192*128
  int r = idx >> 7, c = idx & 127;
  int b = r & 4095;
  P[idx] = (c < 16) ? (_Float16)x[b * 16 + c] : (_Float16)0.f;
}

extern "C" void kernel_launch(void* const* d_in, const int* in_sizes, int n_in,
                              void* d_out, int out_size, void* d_ws, size_t ws_size,
                              hipStream_t stream) {
  const float* x = (const float*)d_in[0];
  const float* Win_f = (const float*)d_in[1];
  const float* bin_f = (const float*)d_in[2];
  const float* Win_b = (const float*)d_in[3];
  const float* bin_b = (const float*)d_in[4];
  const float* Wblk = (const float*)d_in[5];
  const float* bblk = (const float*)d_in[6];
  const float* Wout_f = (const float*)d_in[7];
  const float* bout_f = (const float*)d_in[8];
  const float* Wout_b = (const float*)d_in[9];
  const float* bout_b = (const float*)d_in[10];
  const float* W1 = (const float*)d_in[11];
  const float* W2 = (const float*)d_in[12];
  const float* W3 = (const float*)d_in[13];
  const float* W4 = (const float*)d_in[14];
  const float* b4 = (const float*)d_in[15];
  float* out = (float*)d_out;

  char* ws = (char*)d_ws;
  size_t off = 0;
  auto alloc = [&](size_t bytes) {
    void* p = ws + off;
    off += (bytes + 255) & ~(size_t)255;
    return p;
  };
  _Float16* WblkT = (_Float16*)alloc((size_t)3 * 1024 * 1024 * 2);
  _Float16* WinT = (_Float16*)alloc((size_t)2 * 17 * 1024 * 128 * 2);
  _Float16* P = (_Float16*)alloc((size_t)8192 * 128 * 2);
  _Float16* hA = (_Float16*)alloc((size_t)8192 * 1024 * 2);
  _Float16* hB = (_Float16*)alloc((size_t)8192 * 1024 * 2);
  float* tot = (float*)alloc((size_t)2 * NB * TOTD * 4);

  prep_wblk<<<dim3(3 * 1024 * 1024 / 256), dim3(256), 0, stream>>>(Wblk, WblkT);
  prep_win<<<dim3(2 * 17 * 1024 * 128 / 256), dim3(256), 0, stream>>>(Win_f, Win_b, WinT);
  prep_p<<<dim3(8192 * 128 / 256), dim3(256), 0, stream>>>(x, P);

  dim3 ggrid(64, 8), gblk(256);
  for (int i = 0; i < NLEV; ++i) {
    gemm_k<2, false><<<ggrid, gblk, 0, stream>>>(
        P, PW * 2, WinT + (size_t)i * 1024 * 128, WinT + (size_t)(NLEV + i) * 1024 * 128,
        PW * 2, bin_f + i * H, bin_b + i * H, hA);
    gemm_k<16, true><<<ggrid, gblk, 0, stream>>>(
        hA, H * 2, WblkT, WblkT, H * 2, bblk, bblk, hB);
    gemm_k<16, true><<<ggrid, gblk, 0, stream>>>(
        hB, H * 2, WblkT + (1 << 20), WblkT + (1 << 20), H * 2, bblk + H, bblk + H, hA);
    gemm_k<16, true><<<ggrid, gblk, 0, stream>>>(
        hA, H * 2, WblkT + (2 << 20), WblkT + (2 << 20), H * 2, bblk + 2 * H, bblk + 2 * H, hB);
    outproj_k<<<dim3(2048), dim3(256), 0, stream>>>(
        hB, Wout_f, Wout_b, bout_f, bout_b, i, tot, P);
  }
  attn_k<<<dim3(NB), dim3(128), 0, stream>>>(tot, W1, W2, W3, W4, b4, out);
}